// Round 6
// baseline (130.226 us; speedup 1.0000x reference)
//
#include <hip/hip_runtime.h>
#include <stdint.h>

typedef unsigned short u16;
typedef __attribute__((ext_vector_type(8))) short bf16x8;
typedef __attribute__((ext_vector_type(4))) float f32x4;

typedef __attribute__((address_space(1))) const unsigned char gas_u8;
typedef __attribute__((address_space(3))) unsigned char las_u8;

__device__ __forceinline__ void gload_lds16(const void* g, void* l) {
  __builtin_amdgcn_global_load_lds((const gas_u8*)g, (las_u8*)l, 16, 0, 0);
}

__device__ __forceinline__ u16 f2bf(float f) {
  uint32_t u = __float_as_uint(f);
  u += 0x7fffu + ((u >> 16) & 1u);
  return (u16)(u >> 16);
}
__device__ __forceinline__ float bf2f(u16 v) {
  return __uint_as_float(((uint32_t)v) << 16);
}

// ---------------------------------------------------------------------------
// Merged transpose: blocks 0..63 do W1 [256][1024] -> W1T bf16 [1024][256];
// blocks 64..127 do W2 [1024][256] -> W2T bf16 [256][1024].
// ---------------------------------------------------------------------------
__global__ __launch_bounds__(256, 4)
void transpose_kernel(const float* __restrict__ W1, u16* __restrict__ W1T,
                      const float* __restrict__ W2, u16* __restrict__ W2T) {
  __shared__ u16 tile[64 * 66];
  int b = blockIdx.x;
  const float* src; u16* dst; int R, C, tc, tr;
  if (b < 64) { src = W1; dst = W1T; R = 256; C = 1024; tc = (b & 15) * 64; tr = (b >> 4) * 64; }
  else { b -= 64; src = W2; dst = W2T; R = 1024; C = 256; tc = (b & 3) * 64; tr = (b >> 2) * 64; }
  const int t = threadIdx.x;
  const int c = t & 63, rb = t >> 6;
#pragma unroll
  for (int i = 0; i < 16; ++i) {
    int r = i * 4 + rb;
    tile[r * 66 + c] = f2bf(src[(size_t)(tr + r) * C + tc + c]);
  }
  __syncthreads();
#pragma unroll
  for (int i = 0; i < 16; ++i) {
    int x = i * 4 + rb;
    int y = c;
    dst[(size_t)(tc + x) * R + tr + y] = tile[y * 66 + x];
  }
}

// ---------------------------------------------------------------------------
// Attention + LN1 -> x (bf16 [32768][256]).  One block per board (512 blocks).
// float4 logits gather: 1 load serves all 4 heads. (round-5 verified form)
// ---------------------------------------------------------------------------
__global__ __launch_bounds__(256, 2)
void attn_kernel(const int* __restrict__ piece_indices,
                 const int* __restrict__ abi_idx,
                 const int* __restrict__ ksq,
                 const float* __restrict__ value_table,
                 const float* __restrict__ aw_table,
                 const float* __restrict__ ab_table,
                 const float* __restrict__ scale_p,
                 const float* __restrict__ ln1w, const float* __restrict__ ln1b,
                 u16* __restrict__ xout) {
  __shared__ __align__(16) u16 VT[256 * 64];   // V^T, swizzled 16B chunks
  __shared__ __align__(16) u16 P[4 * 64 * 64]; // P[h][q][k], swizzled 16B chunks
  __shared__ __align__(16) float abt_s[169 * 4];
  __shared__ int pno_s[64];
  __shared__ int pidx_s[64];
  __shared__ float red[4][64][2];
  __shared__ float redA[4][4][64];  // [kg][h][q] partial max
  __shared__ float redB[4][4][64];  // [kg][h][q] partial sum

  const int n = blockIdx.x;
  const int t = threadIdx.x;
  const int h = t >> 6;    // wave id; = kg in gather phase
  const int lane = t & 63; // = q in gather phase
  const int ks = ksq[n];

  if (t < 64) {
    int pi = piece_indices[n * 64 + t];
    pidx_s[t] = pi;
    pno_s[t] = pi - ks * 832;
  }
  for (int i = t; i < 676; i += 256) abt_s[i] = ab_table[i];
  __syncthreads();

  const float scale = scale_p[0];
  const int q = lane, kg = h;

  // ---- logits gather: thread (q,kg) loads k in [16kg,16kg+16) for ALL heads
  float l[4][16];
  {
    const int base = ks * (832 * 832) + pno_s[q] * 832;
#pragma unroll
    for (int j = 0; j < 16; ++j) {
      int k = kg * 16 + j;
      int idx = base + pno_s[k];
      f32x4 aw4 = *(const f32x4*)(aw_table + (size_t)idx * 4);
      int bi = abi_idx[n * 4096 + k * 64 + q];
      f32x4 ab4 = *(const f32x4*)(abt_s + bi * 4);
#pragma unroll
      for (int hh = 0; hh < 4; ++hh) l[hh][j] = (aw4[hh] + ab4[hh]) * scale;
    }
  }

  // ---- V gather (transposed): thread t = feature row of VT ----
  {
    const int feat = t;
#pragma unroll
    for (int c = 0; c < 8; ++c) {
      bf16x8 vv;
#pragma unroll
      for (int j = 0; j < 8; ++j) {
        int k = c * 8 + j;
        float v = value_table[(size_t)pidx_s[k] * 256 + feat];
        vv[j] = (short)f2bf(v);
      }
      int off = feat * 64 + ((c ^ (feat & 7)) << 3);
      *(bf16x8*)(&VT[off]) = vv;
    }
  }

  // ---- distributed softmax across kg ----
#pragma unroll
  for (int hh = 0; hh < 4; ++hh) {
    float m = l[hh][0];
#pragma unroll
    for (int j = 1; j < 16; ++j) m = fmaxf(m, l[hh][j]);
    redA[kg][hh][q] = m;
  }
  __syncthreads();
  float inv[4];
#pragma unroll
  for (int hh = 0; hh < 4; ++hh) {
    float m = fmaxf(fmaxf(redA[0][hh][q], redA[1][hh][q]),
                    fmaxf(redA[2][hh][q], redA[3][hh][q]));
    float s = 0.f;
#pragma unroll
    for (int j = 0; j < 16; ++j) { l[hh][j] = __expf(l[hh][j] - m); s += l[hh][j]; }
    redB[kg][hh][q] = s;
  }
  __syncthreads();
#pragma unroll
  for (int hh = 0; hh < 4; ++hh)
    inv[hh] = 1.f / (redB[0][hh][q] + redB[1][hh][q] + redB[2][hh][q] + redB[3][hh][q]);

  // ---- P write: thread owns k-range [16kg,16kg+16) for all 4 heads ----
#pragma unroll
  for (int hh = 0; hh < 4; ++hh) {
#pragma unroll
    for (int c2 = 0; c2 < 2; ++c2) {
      int c = kg * 2 + c2;
      bf16x8 pv;
#pragma unroll
      for (int j8 = 0; j8 < 8; ++j8) {
        int j = c2 * 8 + j8;
        int k = kg * 16 + j;
        float v = l[hh][j] * inv[hh] + ((k == q) ? 1.f : 0.f);  // +I residual
        pv[j8] = (short)f2bf(v);
      }
      int off = (hh * 64 + q) * 64 + ((c ^ (q & 7)) << 3);
      *(bf16x8*)(&P[off]) = pv;
    }
  }
  __syncthreads();

  // ---- ctx = (P+I) @ V via MFMA; wave h computes head h (64x64, K=64) ----
  const int li = lane & 15, lg = lane >> 4;
  f32x4 acc[4][4] = {};
#pragma unroll
  for (int kst = 0; kst < 2; ++kst) {
    int cg = kst * 4 + lg;
    bf16x8 aF[4], bF[4];
#pragma unroll
    for (int mi = 0; mi < 4; ++mi) {
      int row = mi * 16 + li;
      aF[mi] = *(const bf16x8*)(&P[(h * 64 + row) * 64 + ((cg ^ (row & 7)) << 3)]);
    }
#pragma unroll
    for (int ni = 0; ni < 4; ++ni) {
      int rr = h * 64 + ni * 16 + li;
      bF[ni] = *(const bf16x8*)(&VT[rr * 64 + ((cg ^ (rr & 7)) << 3)]);
    }
#pragma unroll
    for (int mi = 0; mi < 4; ++mi)
#pragma unroll
      for (int ni = 0; ni < 4; ++ni)
        acc[mi][ni] = __builtin_amdgcn_mfma_f32_16x16x32_bf16(aF[mi], bF[ni], acc[mi][ni], 0, 0, 0);
  }

  // ---- LN1 ----
#pragma unroll
  for (int mi = 0; mi < 4; ++mi)
#pragma unroll
    for (int r = 0; r < 4; ++r) {
      float s1 = 0.f, s2 = 0.f;
#pragma unroll
      for (int ni = 0; ni < 4; ++ni) { float v = acc[mi][ni][r]; s1 += v; s2 += v * v; }
#pragma unroll
      for (int mk = 1; mk < 16; mk <<= 1) { s1 += __shfl_xor(s1, mk, 64); s2 += __shfl_xor(s2, mk, 64); }
      if (li == 0) { int q2 = mi * 16 + lg * 4 + r; red[h][q2][0] = s1; red[h][q2][1] = s2; }
    }
  __syncthreads();

  float w_[4], b_[4];
#pragma unroll
  for (int ni = 0; ni < 4; ++ni) {
    int f = h * 64 + ni * 16 + li;
    w_[ni] = ln1w[f]; b_[ni] = ln1b[f];
  }
#pragma unroll
  for (int mi = 0; mi < 4; ++mi)
#pragma unroll
    for (int r = 0; r < 4; ++r) {
      int q2 = mi * 16 + lg * 4 + r;
      float S1 = red[0][q2][0] + red[1][q2][0] + red[2][q2][0] + red[3][q2][0];
      float S2 = red[0][q2][1] + red[1][q2][1] + red[2][q2][1] + red[3][q2][1];
      float mean = S1 * (1.f / 256.f);
      float var = S2 * (1.f / 256.f) - mean * mean;
      float rs = rsqrtf(var + 1e-5f);
      size_t tb = (size_t)(n * 64 + q2) * 256;
#pragma unroll
      for (int ni = 0; ni < 4; ++ni) {
        float xv = (acc[mi][ni][r] - mean) * rs * w_[ni] + b_[ni];
        xout[tb + h * 64 + ni * 16 + li] = f2bf(xv);
      }
    }
}

// ---------------------------------------------------------------------------
// GEMM1: H = relu(X@W1+b1) -> bf16 [32768][1024]
// 128x128 tile, BK=64, 2-PHASE double-buffer with COUNTED vmcnt(8):
// next tile's 8 gload_lds stay in flight while current tile computes.
// LDS 64KB -> 2 blocks/CU.
// ---------------------------------------------------------------------------
__global__ __launch_bounds__(256, 2)
void ffn1_kernel(const u16* __restrict__ X, const u16* __restrict__ W1T,
                 const float* __restrict__ b1, u16* __restrict__ H) {
  __shared__ __align__(16) u16 A_lds[2][128 * 64];
  __shared__ __align__(16) u16 B_lds[2][128 * 64];
  const int t = threadIdx.x;
  const int wv = t >> 6, lane = t & 63;
  const int li = lane & 15, lg = lane >> 4;
  const int wr = wv >> 1, wc = wv & 1;
  const int m0 = blockIdx.x * 128;
  const int n0 = blockIdx.y * 128;
  f32x4 acc[4][4] = {};

#define F1_STAGE(k0, buf)                                                           \
  {                                                                                 \
    _Pragma("unroll")                                                               \
    for (int it = 0; it < 4; ++it) {                                                \
      int idx = it * 256 + t;                                                       \
      int row = idx >> 3, c = idx & 7;                                              \
      const u16* g = X + (size_t)(m0 + row) * 256 + (k0) + ((c ^ (row & 7)) << 3);  \
      gload_lds16(g, (char*)A_lds[buf] + it * 4096 + wv * 1024);                    \
    }                                                                               \
    _Pragma("unroll")                                                               \
    for (int it = 0; it < 4; ++it) {                                                \
      int idx = it * 256 + t;                                                       \
      int row = idx >> 3, c = idx & 7;                                              \
      const u16* g = W1T + (size_t)(n0 + row) * 256 + (k0) + ((c ^ (row & 7)) << 3);\
      gload_lds16(g, (char*)B_lds[buf] + it * 4096 + wv * 1024);                    \
    }                                                                               \
  }

  F1_STAGE(0, 0);
  for (int s = 0; s < 4; ++s) {
    if (s < 3) {
      F1_STAGE((s + 1) * 64, (s + 1) & 1);
      asm volatile("s_waitcnt vmcnt(8)" ::: "memory");
    } else {
      asm volatile("s_waitcnt vmcnt(0)" ::: "memory");
    }
    __builtin_amdgcn_s_barrier();
    const u16* Ab = A_lds[s & 1];
    const u16* Bb = B_lds[s & 1];
#pragma unroll
    for (int kst = 0; kst < 2; ++kst) {
      int cg = kst * 4 + lg;
      bf16x8 aF[4], bF[4];
#pragma unroll
      for (int mi = 0; mi < 4; ++mi) {
        int row = wr * 64 + mi * 16 + li;
        aF[mi] = *(const bf16x8*)(&Ab[row * 64 + ((cg ^ (row & 7)) << 3)]);
      }
#pragma unroll
      for (int ni = 0; ni < 4; ++ni) {
        int row = wc * 64 + ni * 16 + li;
        bF[ni] = *(const bf16x8*)(&Bb[row * 64 + ((cg ^ (row & 7)) << 3)]);
      }
#pragma unroll
      for (int mi = 0; mi < 4; ++mi)
#pragma unroll
        for (int ni = 0; ni < 4; ++ni)
          acc[mi][ni] = __builtin_amdgcn_mfma_f32_16x16x32_bf16(aF[mi], bF[ni], acc[mi][ni], 0, 0, 0);
    }
    __builtin_amdgcn_s_barrier();
  }
#undef F1_STAGE

  float bias[4];
#pragma unroll
  for (int ni = 0; ni < 4; ++ni) bias[ni] = b1[n0 + wc * 64 + ni * 16 + li];
#pragma unroll
  for (int mi = 0; mi < 4; ++mi)
#pragma unroll
    for (int r = 0; r < 4; ++r) {
      int row = m0 + wr * 64 + mi * 16 + lg * 4 + r;
#pragma unroll
      for (int ni = 0; ni < 4; ++ni) {
        float v = fmaxf(acc[mi][ni][r] + bias[ni], 0.f);
        H[(size_t)row * 1024 + n0 + wc * 64 + ni * 16 + li] = f2bf(v);
      }
    }
}

// ---------------------------------------------------------------------------
// GEMM2 + bias + residual + LN2 -> out f32 [32768][256]
// 64x256 tile (full N for fused LN2), K=1024, 2-PHASE counted vmcnt(10).
// LDS: A dbuf 16KB + B dbuf 64KB = 80KB -> 2 blocks/CU; LN2 red[] aliases
// the A staging buffer (free after the K-loop).
// ---------------------------------------------------------------------------
__global__ __launch_bounds__(256, 2)
void ffn2_kernel(const u16* __restrict__ Hm, const u16* __restrict__ W2T,
                 const float* __restrict__ b2, const u16* __restrict__ X,
                 const float* __restrict__ ln2w, const float* __restrict__ ln2b,
                 float* __restrict__ out) {
  __shared__ __align__(16) u16 A_lds[2][64 * 64];
  __shared__ __align__(16) u16 B_lds[2][256 * 64];
  float* red = (float*)&A_lds[0][0];  // [4][64][2] flat, reused post-loop
  const int t = threadIdx.x;
  const int wv = t >> 6, lane = t & 63;
  const int li = lane & 15, lg = lane >> 4;
  const int m0 = blockIdx.x * 64;
  f32x4 acc[4][4] = {};

#define F2_STAGE(k0, buf)                                                           \
  {                                                                                 \
    _Pragma("unroll")                                                               \
    for (int it = 0; it < 2; ++it) {                                                \
      int idx = it * 256 + t;                                                       \
      int row = idx >> 3, c = idx & 7;                                              \
      const u16* g = Hm + (size_t)(m0 + row) * 1024 + (k0) + ((c ^ (row & 7)) << 3);\
      gload_lds16(g, (char*)A_lds[buf] + it * 4096 + wv * 1024);                    \
    }                                                                               \
    _Pragma("unroll")                                                               \
    for (int it = 0; it < 8; ++it) {                                                \
      int idx = it * 256 + t;                                                       \
      int row = idx >> 3, c = idx & 7;                                              \
      const u16* g = W2T + (size_t)row * 1024 + (k0) + ((c ^ (row & 7)) << 3);      \
      gload_lds16(g, (char*)B_lds[buf] + it * 4096 + wv * 1024);                    \
    }                                                                               \
  }

  F2_STAGE(0, 0);
  for (int s = 0; s < 16; ++s) {
    if (s < 15) {
      F2_STAGE((s + 1) * 64, (s + 1) & 1);
      asm volatile("s_waitcnt vmcnt(10)" ::: "memory");
    } else {
      asm volatile("s_waitcnt vmcnt(0)" ::: "memory");
    }
    __builtin_amdgcn_s_barrier();
    const u16* Ab = A_lds[s & 1];
    const u16* Bb = B_lds[s & 1];
#pragma unroll
    for (int kst = 0; kst < 2; ++kst) {
      int cg = kst * 4 + lg;
      bf16x8 aF[4], bF[4];
#pragma unroll
      for (int mi = 0; mi < 4; ++mi) {
        int row = mi * 16 + li;
        aF[mi] = *(const bf16x8*)(&Ab[row * 64 + ((cg ^ (row & 7)) << 3)]);
      }
#pragma unroll
      for (int ni = 0; ni < 4; ++ni) {
        int row = wv * 64 + ni * 16 + li;
        bF[ni] = *(const bf16x8*)(&Bb[row * 64 + ((cg ^ (row & 7)) << 3)]);
      }
#pragma unroll
      for (int mi = 0; mi < 4; ++mi)
#pragma unroll
        for (int ni = 0; ni < 4; ++ni)
          acc[mi][ni] = __builtin_amdgcn_mfma_f32_16x16x32_bf16(aF[mi], bF[ni], acc[mi][ni], 0, 0, 0);
    }
    __builtin_amdgcn_s_barrier();
  }
#undef F2_STAGE
  __syncthreads();  // all compute done before red[] aliases A_lds

  float bias2[4];
#pragma unroll
  for (int ni = 0; ni < 4; ++ni) bias2[ni] = b2[wv * 64 + ni * 16 + li];

#pragma unroll
  for (int mi = 0; mi < 4; ++mi)
#pragma unroll
    for (int r = 0; r < 4; ++r) {
      float s1 = 0.f, s2 = 0.f;
      int row = m0 + mi * 16 + lg * 4 + r;
#pragma unroll
      for (int ni = 0; ni < 4; ++ni) {
        int col = wv * 64 + ni * 16 + li;
        float v = acc[mi][ni][r] + bias2[ni] + bf2f(X[(size_t)row * 256 + col]);
        acc[mi][ni][r] = v;
        s1 += v; s2 += v * v;
      }
#pragma unroll
      for (int mk = 1; mk < 16; mk <<= 1) { s1 += __shfl_xor(s1, mk, 64); s2 += __shfl_xor(s2, mk, 64); }
      if (li == 0) { int q2 = mi * 16 + lg * 4 + r; red[(wv * 64 + q2) * 2 + 0] = s1; red[(wv * 64 + q2) * 2 + 1] = s2; }
    }
  __syncthreads();

  float lw[4], lb[4];
#pragma unroll
  for (int ni = 0; ni < 4; ++ni) {
    int col = wv * 64 + ni * 16 + li;
    lw[ni] = ln2w[col]; lb[ni] = ln2b[col];
  }
#pragma unroll
  for (int mi = 0; mi < 4; ++mi)
#pragma unroll
    for (int r = 0; r < 4; ++r) {
      int q2 = mi * 16 + lg * 4 + r;
      float S1 = red[(0 * 64 + q2) * 2 + 0] + red[(1 * 64 + q2) * 2 + 0] +
                 red[(2 * 64 + q2) * 2 + 0] + red[(3 * 64 + q2) * 2 + 0];
      float S2 = red[(0 * 64 + q2) * 2 + 1] + red[(1 * 64 + q2) * 2 + 1] +
                 red[(2 * 64 + q2) * 2 + 1] + red[(3 * 64 + q2) * 2 + 1];
      float mean = S1 * (1.f / 256.f);
      float var = S2 * (1.f / 256.f) - mean * mean;
      float rs = rsqrtf(var + 1e-5f);
      size_t rbase = (size_t)(m0 + q2) * 256;
#pragma unroll
      for (int ni = 0; ni < 4; ++ni)
        out[rbase + wv * 64 + ni * 16 + li] = (acc[mi][ni][r] - mean) * rs * lw[ni] + lb[ni];
    }
}

// ---------------------------------------------------------------------------
extern "C" void kernel_launch(void* const* d_in, const int* in_sizes, int n_in,
                              void* d_out, int out_size, void* d_ws, size_t ws_size,
                              hipStream_t stream) {
  const int* piece_indices = (const int*)d_in[0];
  const int* abi_idx       = (const int*)d_in[1];
  const int* ksq           = (const int*)d_in[2];
  const float* value_table = (const float*)d_in[3];
  const float* aw_table    = (const float*)d_in[4];
  const float* ab_table    = (const float*)d_in[5];
  const float* attn_scale  = (const float*)d_in[6];
  const float* W1          = (const float*)d_in[7];
  const float* b1          = (const float*)d_in[8];
  const float* W2          = (const float*)d_in[9];
  const float* b2          = (const float*)d_in[10];
  const float* ln1w        = (const float*)d_in[11];
  const float* ln1b        = (const float*)d_in[12];
  const float* ln2w        = (const float*)d_in[13];
  const float* ln2b        = (const float*)d_in[14];

  char* ws = (char*)d_ws;
  u16* W1T = (u16*)(ws);                              // 512 KB  [1024][256] bf16
  u16* W2T = (u16*)(ws + (512 << 10));                // 512 KB  [256][1024] bf16
  u16* X   = (u16*)(ws + (1 << 20));                  // 16 MB   [32768][256] bf16
  u16* Hm  = (u16*)(ws + (1 << 20) + (16 << 20));     // 64 MB   [32768][1024] bf16
  float* out = (float*)d_out;

  transpose_kernel<<<128, 256, 0, stream>>>(W1, W1T, W2, W2T);
  attn_kernel<<<512, 256, 0, stream>>>(piece_indices, abi_idx, ksq, value_table,
                                       aw_table, ab_table, attn_scale, ln1w, ln1b, X);
  ffn1_kernel<<<dim3(256, 8), 256, 0, stream>>>(X, W1T, b1, Hm);
  ffn2_kernel<<<512, 256, 0, stream>>>(Hm, W2T, b2, X, ln2w, ln2b, out);
}

// Round 7
// 119.045 us; speedup vs baseline: 1.0939x; 1.0939x over previous
//
#include <hip/hip_runtime.h>
#include <stdint.h>

typedef unsigned short u16;
typedef __attribute__((ext_vector_type(8))) short bf16x8;
typedef __attribute__((ext_vector_type(4))) float f32x4;

typedef __attribute__((address_space(1))) const unsigned char gas_u8;
typedef __attribute__((address_space(3))) unsigned char las_u8;

__device__ __forceinline__ void gload_lds16(const void* g, void* l) {
  __builtin_amdgcn_global_load_lds((const gas_u8*)g, (las_u8*)l, 16, 0, 0);
}

__device__ __forceinline__ u16 f2bf(float f) {
  uint32_t u = __float_as_uint(f);
  u += 0x7fffu + ((u >> 16) & 1u);
  return (u16)(u >> 16);
}
__device__ __forceinline__ float bf2f(u16 v) {
  return __uint_as_float(((uint32_t)v) << 16);
}

// ---------------------------------------------------------------------------
// Merged transpose: blocks 0..63 do W1 [256][1024] -> W1T bf16 [1024][256];
// blocks 64..127 do W2 [1024][256] -> W2T bf16 [256][1024].
// ---------------------------------------------------------------------------
__global__ __launch_bounds__(256, 4)
void transpose_kernel(const float* __restrict__ W1, u16* __restrict__ W1T,
                      const float* __restrict__ W2, u16* __restrict__ W2T) {
  __shared__ u16 tile[64 * 66];
  int b = blockIdx.x;
  const float* src; u16* dst; int R, C, tc, tr;
  if (b < 64) { src = W1; dst = W1T; R = 256; C = 1024; tc = (b & 15) * 64; tr = (b >> 4) * 64; }
  else { b -= 64; src = W2; dst = W2T; R = 1024; C = 256; tc = (b & 3) * 64; tr = (b >> 2) * 64; }
  const int t = threadIdx.x;
  const int c = t & 63, rb = t >> 6;
#pragma unroll
  for (int i = 0; i < 16; ++i) {
    int r = i * 4 + rb;
    tile[r * 66 + c] = f2bf(src[(size_t)(tr + r) * C + tc + c]);
  }
  __syncthreads();
#pragma unroll
  for (int i = 0; i < 16; ++i) {
    int x = i * 4 + rb;
    int y = c;
    dst[(size_t)(tc + x) * R + tr + y] = tile[y * 66 + x];
  }
}

// ---------------------------------------------------------------------------
// Attention + LN1 -> x (bf16 [32768][256]).  One block per board (512 blocks).
// float4 logits gather: 1 load serves all 4 heads. (round-5 verified form)
// ---------------------------------------------------------------------------
__global__ __launch_bounds__(256, 2)
void attn_kernel(const int* __restrict__ piece_indices,
                 const int* __restrict__ abi_idx,
                 const int* __restrict__ ksq,
                 const float* __restrict__ value_table,
                 const float* __restrict__ aw_table,
                 const float* __restrict__ ab_table,
                 const float* __restrict__ scale_p,
                 const float* __restrict__ ln1w, const float* __restrict__ ln1b,
                 u16* __restrict__ xout) {
  __shared__ __align__(16) u16 VT[256 * 64];   // V^T, swizzled 16B chunks
  __shared__ __align__(16) u16 P[4 * 64 * 64]; // P[h][q][k], swizzled 16B chunks
  __shared__ __align__(16) float abt_s[169 * 4];
  __shared__ int pno_s[64];
  __shared__ int pidx_s[64];
  __shared__ float red[4][64][2];
  __shared__ float redA[4][4][64];  // [kg][h][q] partial max
  __shared__ float redB[4][4][64];  // [kg][h][q] partial sum

  const int n = blockIdx.x;
  const int t = threadIdx.x;
  const int h = t >> 6;    // wave id; = kg in gather phase
  const int lane = t & 63; // = q in gather phase
  const int ks = ksq[n];

  if (t < 64) {
    int pi = piece_indices[n * 64 + t];
    pidx_s[t] = pi;
    pno_s[t] = pi - ks * 832;
  }
  for (int i = t; i < 676; i += 256) abt_s[i] = ab_table[i];
  __syncthreads();

  const float scale = scale_p[0];
  const int q = lane, kg = h;

  // ---- logits gather: thread (q,kg) loads k in [16kg,16kg+16) for ALL heads
  float l[4][16];
  {
    const int base = ks * (832 * 832) + pno_s[q] * 832;
#pragma unroll
    for (int j = 0; j < 16; ++j) {
      int k = kg * 16 + j;
      int idx = base + pno_s[k];
      f32x4 aw4 = *(const f32x4*)(aw_table + (size_t)idx * 4);
      int bi = abi_idx[n * 4096 + k * 64 + q];
      f32x4 ab4 = *(const f32x4*)(abt_s + bi * 4);
#pragma unroll
      for (int hh = 0; hh < 4; ++hh) l[hh][j] = (aw4[hh] + ab4[hh]) * scale;
    }
  }

  // ---- V gather (transposed): thread t = feature row of VT ----
  {
    const int feat = t;
#pragma unroll
    for (int c = 0; c < 8; ++c) {
      bf16x8 vv;
#pragma unroll
      for (int j = 0; j < 8; ++j) {
        int k = c * 8 + j;
        float v = value_table[(size_t)pidx_s[k] * 256 + feat];
        vv[j] = (short)f2bf(v);
      }
      int off = feat * 64 + ((c ^ (feat & 7)) << 3);
      *(bf16x8*)(&VT[off]) = vv;
    }
  }

  // ---- distributed softmax across kg ----
#pragma unroll
  for (int hh = 0; hh < 4; ++hh) {
    float m = l[hh][0];
#pragma unroll
    for (int j = 1; j < 16; ++j) m = fmaxf(m, l[hh][j]);
    redA[kg][hh][q] = m;
  }
  __syncthreads();
  float inv[4];
#pragma unroll
  for (int hh = 0; hh < 4; ++hh) {
    float m = fmaxf(fmaxf(redA[0][hh][q], redA[1][hh][q]),
                    fmaxf(redA[2][hh][q], redA[3][hh][q]));
    float s = 0.f;
#pragma unroll
    for (int j = 0; j < 16; ++j) { l[hh][j] = __expf(l[hh][j] - m); s += l[hh][j]; }
    redB[kg][hh][q] = s;
  }
  __syncthreads();
#pragma unroll
  for (int hh = 0; hh < 4; ++hh)
    inv[hh] = 1.f / (redB[0][hh][q] + redB[1][hh][q] + redB[2][hh][q] + redB[3][hh][q]);

  // ---- P write: thread owns k-range [16kg,16kg+16) for all 4 heads ----
#pragma unroll
  for (int hh = 0; hh < 4; ++hh) {
#pragma unroll
    for (int c2 = 0; c2 < 2; ++c2) {
      int c = kg * 2 + c2;
      bf16x8 pv;
#pragma unroll
      for (int j8 = 0; j8 < 8; ++j8) {
        int j = c2 * 8 + j8;
        int k = kg * 16 + j;
        float v = l[hh][j] * inv[hh] + ((k == q) ? 1.f : 0.f);  // +I residual
        pv[j8] = (short)f2bf(v);
      }
      int off = (hh * 64 + q) * 64 + ((c ^ (q & 7)) << 3);
      *(bf16x8*)(&P[off]) = pv;
    }
  }
  __syncthreads();

  // ---- ctx = (P+I) @ V via MFMA; wave h computes head h (64x64, K=64) ----
  const int li = lane & 15, lg = lane >> 4;
  f32x4 acc[4][4] = {};
#pragma unroll
  for (int kst = 0; kst < 2; ++kst) {
    int cg = kst * 4 + lg;
    bf16x8 aF[4], bF[4];
#pragma unroll
    for (int mi = 0; mi < 4; ++mi) {
      int row = mi * 16 + li;
      aF[mi] = *(const bf16x8*)(&P[(h * 64 + row) * 64 + ((cg ^ (row & 7)) << 3)]);
    }
#pragma unroll
    for (int ni = 0; ni < 4; ++ni) {
      int rr = h * 64 + ni * 16 + li;
      bF[ni] = *(const bf16x8*)(&VT[rr * 64 + ((cg ^ (rr & 7)) << 3)]);
    }
#pragma unroll
    for (int mi = 0; mi < 4; ++mi)
#pragma unroll
      for (int ni = 0; ni < 4; ++ni)
        acc[mi][ni] = __builtin_amdgcn_mfma_f32_16x16x32_bf16(aF[mi], bF[ni], acc[mi][ni], 0, 0, 0);
  }

  // ---- LN1 ----
#pragma unroll
  for (int mi = 0; mi < 4; ++mi)
#pragma unroll
    for (int r = 0; r < 4; ++r) {
      float s1 = 0.f, s2 = 0.f;
#pragma unroll
      for (int ni = 0; ni < 4; ++ni) { float v = acc[mi][ni][r]; s1 += v; s2 += v * v; }
#pragma unroll
      for (int mk = 1; mk < 16; mk <<= 1) { s1 += __shfl_xor(s1, mk, 64); s2 += __shfl_xor(s2, mk, 64); }
      if (li == 0) { int q2 = mi * 16 + lg * 4 + r; red[h][q2][0] = s1; red[h][q2][1] = s2; }
    }
  __syncthreads();

  float w_[4], b_[4];
#pragma unroll
  for (int ni = 0; ni < 4; ++ni) {
    int f = h * 64 + ni * 16 + li;
    w_[ni] = ln1w[f]; b_[ni] = ln1b[f];
  }
#pragma unroll
  for (int mi = 0; mi < 4; ++mi)
#pragma unroll
    for (int r = 0; r < 4; ++r) {
      int q2 = mi * 16 + lg * 4 + r;
      float S1 = red[0][q2][0] + red[1][q2][0] + red[2][q2][0] + red[3][q2][0];
      float S2 = red[0][q2][1] + red[1][q2][1] + red[2][q2][1] + red[3][q2][1];
      float mean = S1 * (1.f / 256.f);
      float var = S2 * (1.f / 256.f) - mean * mean;
      float rs = rsqrtf(var + 1e-5f);
      size_t tb = (size_t)(n * 64 + q2) * 256;
#pragma unroll
      for (int ni = 0; ni < 4; ++ni) {
        float xv = (acc[mi][ni][r] - mean) * rs * w_[ni] + b_[ni];
        xout[tb + h * 64 + ni * 16 + li] = f2bf(xv);
      }
    }
}

// ---------------------------------------------------------------------------
// FUSED FFN: out = LN2( relu(X@W1+b1)@W2 + b2 + X ).  Block = 64 rows.
// X tile staged to LDS ONCE (32 KB); dff processed in 16 chunks of 64:
//   stage W1T chunk (32 KB) -> GEMM1 -> relu+bias -> H chunk to LDS (8 KB)
//   stage W2T chunk into the SAME W buffer -> GEMM2 accumulates in regs.
// No Hm HBM round-trip, no X re-reads (residual read from LDS too).
// LDS = 74 KB -> 2 blocks/CU.
// ---------------------------------------------------------------------------
__global__ __launch_bounds__(256, 2)
void ffn_fused_kernel(const u16* __restrict__ X, const u16* __restrict__ W1T,
                      const u16* __restrict__ W2T,
                      const float* __restrict__ b1, const float* __restrict__ b2,
                      const float* __restrict__ ln2w, const float* __restrict__ ln2b,
                      float* __restrict__ out) {
  __shared__ __align__(16) u16 Xl[64 * 256];  // 32 KB, 32 chunks/row, XOR-swz
  __shared__ __align__(16) u16 Wb[64 * 256];  // 32 KB, W1Tc [64][256] or W2Tc [256][64]
  __shared__ __align__(16) u16 Hb[64 * 64];   // 8 KB, H chunk, XOR-swz
  __shared__ float red[4][64][2];

  const int t = threadIdx.x;
  const int wv = t >> 6, lane = t & 63;
  const int li = lane & 15, lg = lane >> 4;
  const int m0 = blockIdx.x * 64;
  f32x4 oacc[4][4] = {};

  // ---- stage X tile once: 64 rows x 256 k, 2048 16B chunks ----
#pragma unroll
  for (int it = 0; it < 8; ++it) {
    int idx = it * 256 + t;
    int row = idx >> 5, c = idx & 31;
    const u16* g = X + (size_t)(m0 + row) * 256 + (((c ^ (row & 7)) & 31) << 3);
    gload_lds16(g, (char*)Xl + it * 4096 + wv * 1024);
  }

  for (int ch = 0; ch < 16; ++ch) {
    // ---- stage W1T chunk: rows ch*64.., [64][256] ----
#pragma unroll
    for (int it = 0; it < 8; ++it) {
      int idx = it * 256 + t;
      int row = idx >> 5, c = idx & 31;
      const u16* g = W1T + (size_t)(ch * 64 + row) * 256 + (((c ^ (row & 7)) & 31) << 3);
      gload_lds16(g, (char*)Wb + it * 4096 + wv * 1024);
    }
    __syncthreads();  // X + W1Tc ready (drains vmcnt)

    // ---- GEMM1: wave wv computes H cols [wv*16, wv*16+16), K=256 ----
    f32x4 hacc[4] = {};
#pragma unroll
    for (int kst = 0; kst < 8; ++kst) {
      int cg = kst * 4 + lg;
      bf16x8 aF[4], bF;
      {
        int brow = wv * 16 + li;
        bF = *(const bf16x8*)((char*)Wb + brow * 512 + (((cg ^ (brow & 7)) & 31) << 4));
      }
#pragma unroll
      for (int mi = 0; mi < 4; ++mi) {
        int row = mi * 16 + li;
        aF[mi] = *(const bf16x8*)((char*)Xl + row * 512 + (((cg ^ (row & 7)) & 31) << 4));
      }
#pragma unroll
      for (int mi = 0; mi < 4; ++mi)
        hacc[mi] = __builtin_amdgcn_mfma_f32_16x16x32_bf16(aF[mi], bF, hacc[mi], 0, 0, 0);
    }
    __syncthreads();  // all waves done reading W1Tc; H buffer free

    // ---- relu + bias -> H chunk LDS;  stage W2T chunk into Wb ----
    {
      float bv = b1[ch * 64 + wv * 16 + li];
      int col = wv * 16 + li;
      int c2 = col >> 3;
#pragma unroll
      for (int mi = 0; mi < 4; ++mi)
#pragma unroll
        for (int r = 0; r < 4; ++r) {
          int row = mi * 16 + lg * 4 + r;
          float v = fmaxf(hacc[mi][r] + bv, 0.f);
          *(u16*)((char*)Hb + row * 128 + ((c2 ^ (row & 7)) << 4) + (col & 7) * 2) = f2bf(v);
        }
    }
#pragma unroll
    for (int it = 0; it < 8; ++it) {
      int idx = it * 256 + t;
      int row = idx >> 3, c = idx & 7;
      const u16* g = W2T + (size_t)row * 1024 + ch * 64 + ((c ^ (row & 7)) << 3);
      gload_lds16(g, (char*)Wb + it * 4096 + wv * 1024);
    }
    __syncthreads();  // H + W2Tc ready (drains vmcnt + lgkm)

    // ---- GEMM2 partial: oacc += H(64x64) @ W2Tc; wave wv owns out cols wv*64.. ----
#pragma unroll
    for (int kst = 0; kst < 2; ++kst) {
      int cg = kst * 4 + lg;
      bf16x8 aF[4], bF[4];
#pragma unroll
      for (int mi = 0; mi < 4; ++mi) {
        int row = mi * 16 + li;
        aF[mi] = *(const bf16x8*)((char*)Hb + row * 128 + (((cg ^ (row & 7)) & 7) << 4));
      }
#pragma unroll
      for (int ni = 0; ni < 4; ++ni) {
        int row = wv * 64 + ni * 16 + li;
        bF[ni] = *(const bf16x8*)((char*)Wb + row * 128 + (((cg ^ (row & 7)) & 7) << 4));
      }
#pragma unroll
      for (int mi = 0; mi < 4; ++mi)
#pragma unroll
        for (int ni = 0; ni < 4; ++ni)
          oacc[mi][ni] = __builtin_amdgcn_mfma_f32_16x16x32_bf16(aF[mi], bF[ni], oacc[mi][ni], 0, 0, 0);
    }
    __syncthreads();  // Wb + Hb reads done -> next chunk may overwrite
  }

  // ---- epilogue: bias + residual (from Xl) + LN2 ----
  float bias2[4];
#pragma unroll
  for (int ni = 0; ni < 4; ++ni) bias2[ni] = b2[wv * 64 + ni * 16 + li];

#pragma unroll
  for (int mi = 0; mi < 4; ++mi)
#pragma unroll
    for (int r = 0; r < 4; ++r) {
      float s1 = 0.f, s2 = 0.f;
      int row = mi * 16 + lg * 4 + r;
#pragma unroll
      for (int ni = 0; ni < 4; ++ni) {
        int col = wv * 64 + ni * 16 + li;
        int cc = col >> 3;
        u16 xres = *(const u16*)((char*)Xl + row * 512 + (((cc ^ (row & 7)) & 31) << 4) + (col & 7) * 2);
        float v = oacc[mi][ni][r] + bias2[ni] + bf2f(xres);
        oacc[mi][ni][r] = v;
        s1 += v; s2 += v * v;
      }
#pragma unroll
      for (int mk = 1; mk < 16; mk <<= 1) { s1 += __shfl_xor(s1, mk, 64); s2 += __shfl_xor(s2, mk, 64); }
      if (li == 0) { int q2 = mi * 16 + lg * 4 + r; red[wv][q2][0] = s1; red[wv][q2][1] = s2; }
    }
  __syncthreads();

  float lw[4], lb[4];
#pragma unroll
  for (int ni = 0; ni < 4; ++ni) {
    int col = wv * 64 + ni * 16 + li;
    lw[ni] = ln2w[col]; lb[ni] = ln2b[col];
  }
#pragma unroll
  for (int mi = 0; mi < 4; ++mi)
#pragma unroll
    for (int r = 0; r < 4; ++r) {
      int q2 = mi * 16 + lg * 4 + r;
      float S1 = red[0][q2][0] + red[1][q2][0] + red[2][q2][0] + red[3][q2][0];
      float S2 = red[0][q2][1] + red[1][q2][1] + red[2][q2][1] + red[3][q2][1];
      float mean = S1 * (1.f / 256.f);
      float var = S2 * (1.f / 256.f) - mean * mean;
      float rs = rsqrtf(var + 1e-5f);
      size_t rbase = (size_t)(m0 + q2) * 256;
#pragma unroll
      for (int ni = 0; ni < 4; ++ni)
        out[rbase + wv * 64 + ni * 16 + li] = (oacc[mi][ni][r] - mean) * rs * lw[ni] + lb[ni];
    }
}

// ---------------------------------------------------------------------------
extern "C" void kernel_launch(void* const* d_in, const int* in_sizes, int n_in,
                              void* d_out, int out_size, void* d_ws, size_t ws_size,
                              hipStream_t stream) {
  const int* piece_indices = (const int*)d_in[0];
  const int* abi_idx       = (const int*)d_in[1];
  const int* ksq           = (const int*)d_in[2];
  const float* value_table = (const float*)d_in[3];
  const float* aw_table    = (const float*)d_in[4];
  const float* ab_table    = (const float*)d_in[5];
  const float* attn_scale  = (const float*)d_in[6];
  const float* W1          = (const float*)d_in[7];
  const float* b1          = (const float*)d_in[8];
  const float* W2          = (const float*)d_in[9];
  const float* b2          = (const float*)d_in[10];
  const float* ln1w        = (const float*)d_in[11];
  const float* ln1b        = (const float*)d_in[12];
  const float* ln2w        = (const float*)d_in[13];
  const float* ln2b        = (const float*)d_in[14];

  char* ws = (char*)d_ws;
  u16* W1T = (u16*)(ws);                              // 512 KB  [1024][256] bf16
  u16* W2T = (u16*)(ws + (512 << 10));                // 512 KB  [256][1024] bf16
  u16* X   = (u16*)(ws + (1 << 20));                  // 16 MB   [32768][256] bf16
  float* out = (float*)d_out;

  transpose_kernel<<<128, 256, 0, stream>>>(W1, W1T, W2, W2T);
  attn_kernel<<<512, 256, 0, stream>>>(piece_indices, abi_idx, ksq, value_table,
                                       aw_table, ab_table, attn_scale, ln1w, ln1b, X);
  ffn_fused_kernel<<<512, 256, 0, stream>>>(X, W1T, W2T, b1, b2, ln2w, ln2b, out);
}

// Round 8
// 115.164 us; speedup vs baseline: 1.1308x; 1.0337x over previous
//
#include <hip/hip_runtime.h>
#include <stdint.h>

typedef unsigned short u16;
typedef __attribute__((ext_vector_type(8))) short bf16x8;
typedef __attribute__((ext_vector_type(4))) float f32x4;

typedef __attribute__((address_space(1))) const unsigned char gas_u8;
typedef __attribute__((address_space(3))) unsigned char las_u8;

__device__ __forceinline__ void gload_lds16(const void* g, void* l) {
  __builtin_amdgcn_global_load_lds((const gas_u8*)g, (las_u8*)l, 16, 0, 0);
}

__device__ __forceinline__ u16 f2bf(float f) {
  uint32_t u = __float_as_uint(f);
  u += 0x7fffu + ((u >> 16) & 1u);
  return (u16)(u >> 16);
}
__device__ __forceinline__ float bf2f(u16 v) {
  return __uint_as_float(((uint32_t)v) << 16);
}

// ---------------------------------------------------------------------------
// Merged transpose: blocks 0..63 do W1 [256][1024] -> W1T bf16 [1024][256];
// blocks 64..127 do W2 [1024][256] -> W2T bf16 [256][1024].
// ---------------------------------------------------------------------------
__global__ __launch_bounds__(256, 4)
void transpose_kernel(const float* __restrict__ W1, u16* __restrict__ W1T,
                      const float* __restrict__ W2, u16* __restrict__ W2T) {
  __shared__ u16 tile[64 * 66];
  int b = blockIdx.x;
  const float* src; u16* dst; int R, C, tc, tr;
  if (b < 64) { src = W1; dst = W1T; R = 256; C = 1024; tc = (b & 15) * 64; tr = (b >> 4) * 64; }
  else { b -= 64; src = W2; dst = W2T; R = 1024; C = 256; tc = (b & 3) * 64; tr = (b >> 2) * 64; }
  const int t = threadIdx.x;
  const int c = t & 63, rb = t >> 6;
#pragma unroll
  for (int i = 0; i < 16; ++i) {
    int r = i * 4 + rb;
    tile[r * 66 + c] = f2bf(src[(size_t)(tr + r) * C + tc + c]);
  }
  __syncthreads();
#pragma unroll
  for (int i = 0; i < 16; ++i) {
    int x = i * 4 + rb;
    int y = c;
    dst[(size_t)(tc + x) * R + tr + y] = tile[y * 66 + x];
  }
}

// ---------------------------------------------------------------------------
// MEGA KERNEL: attention + LN1 + fused FFN + LN2.  One block per board.
// x (LN1 out) never touches HBM: written to LDS Xl (aliasing dead P region).
// SMEM layout (78 KB, 2 blocks/CU):
//   [0,32K)    BufA: attn VT          | ffn Wb (W1T/W2T chunk)
//   [32K,64K)  BufB: attn P           | ffn Xl (x tile)
//   [64K,78K)  C:   abt|pno|pidx|redA|redB|red  | ffn Hb + red
// ---------------------------------------------------------------------------
#define SM_BASE 65536
#define OFF_ABT  (SM_BASE + 0)      // f32[676]   2704 B
#define OFF_PNO  (SM_BASE + 2704)   // int[64]     256 B
#define OFF_PIDX (SM_BASE + 2960)   // int[64]     256 B
#define OFF_REDA (SM_BASE + 3216)   // f32[4][4][64] 4096 B
#define OFF_REDB (SM_BASE + 7312)   // f32[4][4][64] 4096 B
#define OFF_RED  (SM_BASE + 11408)  // f32[4][64][2] 2048 B
#define OFF_HB   (SM_BASE + 0)      // u16[64][64] 8192 B (ffn phase only)

__global__ __launch_bounds__(256, 2)
void mega_kernel(const int* __restrict__ piece_indices,
                 const int* __restrict__ abi_idx,
                 const int* __restrict__ ksq,
                 const float* __restrict__ value_table,
                 const float* __restrict__ aw_table,
                 const float* __restrict__ ab_table,
                 const float* __restrict__ scale_p,
                 const float* __restrict__ ln1w, const float* __restrict__ ln1b,
                 const u16* __restrict__ W1T, const u16* __restrict__ W2T,
                 const float* __restrict__ b1, const float* __restrict__ b2,
                 const float* __restrict__ ln2w, const float* __restrict__ ln2b,
                 float* __restrict__ out) {
  __shared__ __align__(16) char SMEM[79872];
  u16* VT = (u16*)(SMEM);            // attn phase
  u16* P  = (u16*)(SMEM + 32768);    // attn phase
  float* abt_s = (float*)(SMEM + OFF_ABT);
  int* pno_s   = (int*)(SMEM + OFF_PNO);
  int* pidx_s  = (int*)(SMEM + OFF_PIDX);
  float* redA  = (float*)(SMEM + OFF_REDA);  // [kg][h][q]
  float* redB  = (float*)(SMEM + OFF_REDB);
  float* red   = (float*)(SMEM + OFF_RED);   // [w][q2][2]

  const int n = blockIdx.x;
  const int t = threadIdx.x;
  const int h = t >> 6;    // wave id; = kg in gather phase
  const int lane = t & 63; // = q in gather phase
  const int ks = ksq[n];

  if (t < 64) {
    int pi = piece_indices[n * 64 + t];
    pidx_s[t] = pi;
    pno_s[t] = pi - ks * 832;
  }
  for (int i = t; i < 676; i += 256) abt_s[i] = ab_table[i];
  __syncthreads();

  const float scale = scale_p[0];
  const int q = lane, kg = h;

  // ---- logits gather: thread (q,kg) loads k in [16kg,16kg+16) for ALL heads
  float l[4][16];
  {
    const int base = ks * (832 * 832) + pno_s[q] * 832;
#pragma unroll
    for (int j = 0; j < 16; ++j) {
      int k = kg * 16 + j;
      int idx = base + pno_s[k];
      f32x4 aw4 = *(const f32x4*)(aw_table + (size_t)idx * 4);
      int bi = abi_idx[n * 4096 + k * 64 + q];
      f32x4 ab4 = *(const f32x4*)(abt_s + bi * 4);
#pragma unroll
      for (int hh = 0; hh < 4; ++hh) l[hh][j] = (aw4[hh] + ab4[hh]) * scale;
    }
  }

  // ---- V gather (transposed): thread t = feature row of VT ----
  {
    const int feat = t;
#pragma unroll
    for (int c = 0; c < 8; ++c) {
      bf16x8 vv;
#pragma unroll
      for (int j = 0; j < 8; ++j) {
        int k = c * 8 + j;
        float v = value_table[(size_t)pidx_s[k] * 256 + feat];
        vv[j] = (short)f2bf(v);
      }
      int off = feat * 64 + ((c ^ (feat & 7)) << 3);
      *(bf16x8*)(&VT[off]) = vv;
    }
  }

  // ---- distributed softmax across kg ----
#pragma unroll
  for (int hh = 0; hh < 4; ++hh) {
    float m = l[hh][0];
#pragma unroll
    for (int j = 1; j < 16; ++j) m = fmaxf(m, l[hh][j]);
    redA[(kg * 4 + hh) * 64 + q] = m;
  }
  __syncthreads();
  float inv[4];
#pragma unroll
  for (int hh = 0; hh < 4; ++hh) {
    float m = fmaxf(fmaxf(redA[(0 * 4 + hh) * 64 + q], redA[(1 * 4 + hh) * 64 + q]),
                    fmaxf(redA[(2 * 4 + hh) * 64 + q], redA[(3 * 4 + hh) * 64 + q]));
    float s = 0.f;
#pragma unroll
    for (int j = 0; j < 16; ++j) { l[hh][j] = __expf(l[hh][j] - m); s += l[hh][j]; }
    redB[(kg * 4 + hh) * 64 + q] = s;
  }
  __syncthreads();
#pragma unroll
  for (int hh = 0; hh < 4; ++hh)
    inv[hh] = 1.f / (redB[(0 * 4 + hh) * 64 + q] + redB[(1 * 4 + hh) * 64 + q] +
                     redB[(2 * 4 + hh) * 64 + q] + redB[(3 * 4 + hh) * 64 + q]);

  // ---- P write: thread owns k-range [16kg,16kg+16) for all 4 heads ----
#pragma unroll
  for (int hh = 0; hh < 4; ++hh) {
#pragma unroll
    for (int c2 = 0; c2 < 2; ++c2) {
      int c = kg * 2 + c2;
      bf16x8 pv;
#pragma unroll
      for (int j8 = 0; j8 < 8; ++j8) {
        int j = c2 * 8 + j8;
        int k = kg * 16 + j;
        float v = l[hh][j] * inv[hh] + ((k == q) ? 1.f : 0.f);  // +I residual
        pv[j8] = (short)f2bf(v);
      }
      int off = (hh * 64 + q) * 64 + ((c ^ (q & 7)) << 3);
      *(bf16x8*)(&P[off]) = pv;
    }
  }
  __syncthreads();

  // ---- ctx = (P+I) @ V via MFMA; wave h computes head h ----
  const int li = lane & 15, lg = lane >> 4;
  f32x4 acc[4][4] = {};
#pragma unroll
  for (int kst = 0; kst < 2; ++kst) {
    int cg = kst * 4 + lg;
    bf16x8 aF[4], bF[4];
#pragma unroll
    for (int mi = 0; mi < 4; ++mi) {
      int row = mi * 16 + li;
      aF[mi] = *(const bf16x8*)(&P[(h * 64 + row) * 64 + ((cg ^ (row & 7)) << 3)]);
    }
#pragma unroll
    for (int ni = 0; ni < 4; ++ni) {
      int rr = h * 64 + ni * 16 + li;
      bF[ni] = *(const bf16x8*)(&VT[rr * 64 + ((cg ^ (rr & 7)) << 3)]);
    }
#pragma unroll
    for (int mi = 0; mi < 4; ++mi)
#pragma unroll
      for (int ni = 0; ni < 4; ++ni)
        acc[mi][ni] = __builtin_amdgcn_mfma_f32_16x16x32_bf16(aF[mi], bF[ni], acc[mi][ni], 0, 0, 0);
  }

  // ---- LN1 ----
#pragma unroll
  for (int mi = 0; mi < 4; ++mi)
#pragma unroll
    for (int r = 0; r < 4; ++r) {
      float s1 = 0.f, s2 = 0.f;
#pragma unroll
      for (int ni = 0; ni < 4; ++ni) { float v = acc[mi][ni][r]; s1 += v; s2 += v * v; }
#pragma unroll
      for (int mk = 1; mk < 16; mk <<= 1) { s1 += __shfl_xor(s1, mk, 64); s2 += __shfl_xor(s2, mk, 64); }
      if (li == 0) { int q2 = mi * 16 + lg * 4 + r; red[(h * 64 + q2) * 2 + 0] = s1; red[(h * 64 + q2) * 2 + 1] = s2; }
    }
  __syncthreads();   // all MFMA reads of P/VT done; red ready

  // x (LN1 out) -> Xl (aliases P region), FFN swizzled layout
  u16* Xl = (u16*)(SMEM + 32768);
  {
    float w_[4], b_[4];
#pragma unroll
    for (int ni = 0; ni < 4; ++ni) {
      int f = h * 64 + ni * 16 + li;
      w_[ni] = ln1w[f]; b_[ni] = ln1b[f];
    }
#pragma unroll
    for (int mi = 0; mi < 4; ++mi)
#pragma unroll
      for (int r = 0; r < 4; ++r) {
        int q2 = mi * 16 + lg * 4 + r;
        float S1 = red[(0 * 64 + q2) * 2] + red[(1 * 64 + q2) * 2] +
                   red[(2 * 64 + q2) * 2] + red[(3 * 64 + q2) * 2];
        float S2 = red[(0 * 64 + q2) * 2 + 1] + red[(1 * 64 + q2) * 2 + 1] +
                   red[(2 * 64 + q2) * 2 + 1] + red[(3 * 64 + q2) * 2 + 1];
        float mean = S1 * (1.f / 256.f);
        float var = S2 * (1.f / 256.f) - mean * mean;
        float rs = rsqrtf(var + 1e-5f);
#pragma unroll
        for (int ni = 0; ni < 4; ++ni) {
          int col = h * 64 + ni * 16 + li;
          float xv = (acc[mi][ni][r] - mean) * rs * w_[ni] + b_[ni];
          int cc = col >> 3;
          *(u16*)((char*)Xl + q2 * 512 + (((cc ^ (q2 & 7)) & 31) << 4) + (col & 7) * 2) = f2bf(xv);
        }
      }
  }

  // =================== FFN phase ===================
  u16* Wb = (u16*)(SMEM);           // aliases dead VT
  u16* Hb = (u16*)(SMEM + OFF_HB);  // aliases dead abt/redA
  const int wv = h;
  f32x4 oacc[4][4] = {};

  for (int ch = 0; ch < 16; ++ch) {
    // stage W1T chunk [64][256]
#pragma unroll
    for (int it = 0; it < 8; ++it) {
      int idx = it * 256 + t;
      int row = idx >> 5, c = idx & 31;
      const u16* g = W1T + (size_t)(ch * 64 + row) * 256 + (((c ^ (row & 7)) & 31) << 3);
      gload_lds16(g, (char*)Wb + it * 4096 + wv * 1024);
    }
    __syncthreads();  // Xl writes (+first iter) / prev GEMM2 reads + stage drain

    // GEMM1: wave wv computes H cols [wv*16, wv*16+16), K=256
    f32x4 hacc[4] = {};
#pragma unroll
    for (int kst = 0; kst < 8; ++kst) {
      int cg = kst * 4 + lg;
      bf16x8 aF[4], bF;
      {
        int brow = wv * 16 + li;
        bF = *(const bf16x8*)((char*)Wb + brow * 512 + (((cg ^ (brow & 7)) & 31) << 4));
      }
#pragma unroll
      for (int mi = 0; mi < 4; ++mi) {
        int row = mi * 16 + li;
        aF[mi] = *(const bf16x8*)((char*)Xl + row * 512 + (((cg ^ (row & 7)) & 31) << 4));
      }
#pragma unroll
      for (int mi = 0; mi < 4; ++mi)
        hacc[mi] = __builtin_amdgcn_mfma_f32_16x16x32_bf16(aF[mi], bF, hacc[mi], 0, 0, 0);
    }
    __syncthreads();  // W1Tc reads done; Hb free

    // relu + bias -> H chunk LDS; stage W2T chunk into Wb
    {
      float bv = b1[ch * 64 + wv * 16 + li];
      int col = wv * 16 + li;
      int c2 = col >> 3;
#pragma unroll
      for (int mi = 0; mi < 4; ++mi)
#pragma unroll
        for (int r = 0; r < 4; ++r) {
          int row = mi * 16 + lg * 4 + r;
          float v = fmaxf(hacc[mi][r] + bv, 0.f);
          *(u16*)((char*)Hb + row * 128 + ((c2 ^ (row & 7)) << 4) + (col & 7) * 2) = f2bf(v);
        }
    }
#pragma unroll
    for (int it = 0; it < 8; ++it) {
      int idx = it * 256 + t;
      int row = idx >> 3, c = idx & 7;
      const u16* g = W2T + (size_t)row * 1024 + ch * 64 + ((c ^ (row & 7)) << 3);
      gload_lds16(g, (char*)Wb + it * 4096 + wv * 1024);
    }
    __syncthreads();  // H + W2Tc ready

    // GEMM2 partial: oacc += H(64x64) @ W2Tc
#pragma unroll
    for (int kst = 0; kst < 2; ++kst) {
      int cg = kst * 4 + lg;
      bf16x8 aF[4], bF[4];
#pragma unroll
      for (int mi = 0; mi < 4; ++mi) {
        int row = mi * 16 + li;
        aF[mi] = *(const bf16x8*)((char*)Hb + row * 128 + (((cg ^ (row & 7)) & 7) << 4));
      }
#pragma unroll
      for (int ni = 0; ni < 4; ++ni) {
        int row = wv * 64 + ni * 16 + li;
        bF[ni] = *(const bf16x8*)((char*)Wb + row * 128 + (((cg ^ (row & 7)) & 7) << 4));
      }
#pragma unroll
      for (int mi = 0; mi < 4; ++mi)
#pragma unroll
        for (int ni = 0; ni < 4; ++ni)
          oacc[mi][ni] = __builtin_amdgcn_mfma_f32_16x16x32_bf16(aF[mi], bF[ni], oacc[mi][ni], 0, 0, 0);
    }
    __syncthreads();  // Wb/Hb reads done -> next chunk overwrite safe
  }

  // ---- epilogue: bias + residual (from Xl) + LN2 ----
  float bias2[4];
#pragma unroll
  for (int ni = 0; ni < 4; ++ni) bias2[ni] = b2[wv * 64 + ni * 16 + li];

#pragma unroll
  for (int mi = 0; mi < 4; ++mi)
#pragma unroll
    for (int r = 0; r < 4; ++r) {
      float s1 = 0.f, s2 = 0.f;
      int row = mi * 16 + lg * 4 + r;
#pragma unroll
      for (int ni = 0; ni < 4; ++ni) {
        int col = wv * 64 + ni * 16 + li;
        int cc = col >> 3;
        u16 xres = *(const u16*)((char*)Xl + row * 512 + (((cc ^ (row & 7)) & 31) << 4) + (col & 7) * 2);
        float v = oacc[mi][ni][r] + bias2[ni] + bf2f(xres);
        oacc[mi][ni][r] = v;
        s1 += v; s2 += v * v;
      }
#pragma unroll
      for (int mk = 1; mk < 16; mk <<= 1) { s1 += __shfl_xor(s1, mk, 64); s2 += __shfl_xor(s2, mk, 64); }
      if (li == 0) { int q2 = mi * 16 + lg * 4 + r; red[(wv * 64 + q2) * 2 + 0] = s1; red[(wv * 64 + q2) * 2 + 1] = s2; }
    }
  __syncthreads();

  float lw[4], lb[4];
#pragma unroll
  for (int ni = 0; ni < 4; ++ni) {
    int col = wv * 64 + ni * 16 + li;
    lw[ni] = ln2w[col]; lb[ni] = ln2b[col];
  }
#pragma unroll
  for (int mi = 0; mi < 4; ++mi)
#pragma unroll
    for (int r = 0; r < 4; ++r) {
      int q2 = mi * 16 + lg * 4 + r;
      float S1 = red[(0 * 64 + q2) * 2] + red[(1 * 64 + q2) * 2] +
                 red[(2 * 64 + q2) * 2] + red[(3 * 64 + q2) * 2];
      float S2 = red[(0 * 64 + q2) * 2 + 1] + red[(1 * 64 + q2) * 2 + 1] +
                 red[(2 * 64 + q2) * 2 + 1] + red[(3 * 64 + q2) * 2 + 1];
      float mean = S1 * (1.f / 256.f);
      float var = S2 * (1.f / 256.f) - mean * mean;
      float rs = rsqrtf(var + 1e-5f);
      size_t rbase = (size_t)(n * 64 + q2) * 256;
#pragma unroll
      for (int ni = 0; ni < 4; ++ni)
        out[rbase + wv * 64 + ni * 16 + li] = (oacc[mi][ni][r] - mean) * rs * lw[ni] + lb[ni];
    }
}

// ---------------------------------------------------------------------------
extern "C" void kernel_launch(void* const* d_in, const int* in_sizes, int n_in,
                              void* d_out, int out_size, void* d_ws, size_t ws_size,
                              hipStream_t stream) {
  const int* piece_indices = (const int*)d_in[0];
  const int* abi_idx       = (const int*)d_in[1];
  const int* ksq           = (const int*)d_in[2];
  const float* value_table = (const float*)d_in[3];
  const float* aw_table    = (const float*)d_in[4];
  const float* ab_table    = (const float*)d_in[5];
  const float* attn_scale  = (const float*)d_in[6];
  const float* W1          = (const float*)d_in[7];
  const float* b1          = (const float*)d_in[8];
  const float* W2          = (const float*)d_in[9];
  const float* b2          = (const float*)d_in[10];
  const float* ln1w        = (const float*)d_in[11];
  const float* ln1b        = (const float*)d_in[12];
  const float* ln2w        = (const float*)d_in[13];
  const float* ln2b        = (const float*)d_in[14];

  char* ws = (char*)d_ws;
  u16* W1T = (u16*)(ws);                 // 512 KB  [1024][256] bf16
  u16* W2T = (u16*)(ws + (512 << 10));   // 512 KB  [256][1024] bf16
  float* out = (float*)d_out;

  transpose_kernel<<<128, 256, 0, stream>>>(W1, W1T, W2, W2T);
  mega_kernel<<<512, 256, 0, stream>>>(piece_indices, abi_idx, ksq, value_table,
                                       aw_table, ab_table, attn_scale, ln1w, ln1b,
                                       W1T, W2T, b1, b2, ln2w, ln2b, out);
}

// Round 9
// 109.977 us; speedup vs baseline: 1.1841x; 1.0472x over previous
//
#include <hip/hip_runtime.h>
#include <stdint.h>

typedef unsigned short u16;
typedef __attribute__((ext_vector_type(8))) short bf16x8;
typedef __attribute__((ext_vector_type(4))) float f32x4;

typedef __attribute__((address_space(1))) const unsigned char gas_u8;
typedef __attribute__((address_space(3))) unsigned char las_u8;

__device__ __forceinline__ void gload_lds16(const void* g, void* l) {
  __builtin_amdgcn_global_load_lds((const gas_u8*)g, (las_u8*)l, 16, 0, 0);
}

__device__ __forceinline__ u16 f2bf(float f) {
  uint32_t u = __float_as_uint(f);
  u += 0x7fffu + ((u >> 16) & 1u);
  return (u16)(u >> 16);
}
__device__ __forceinline__ float bf2f(u16 v) {
  return __uint_as_float(((uint32_t)v) << 16);
}

// ---------------------------------------------------------------------------
// Merged transpose: blocks 0..63 do W1 [256][1024] -> W1T bf16 [1024][256];
// blocks 64..127 do W2 [1024][256] -> W2T bf16 [256][1024].
// ---------------------------------------------------------------------------
__global__ __launch_bounds__(256, 4)
void transpose_kernel(const float* __restrict__ W1, u16* __restrict__ W1T,
                      const float* __restrict__ W2, u16* __restrict__ W2T) {
  __shared__ u16 tile[64 * 66];
  int b = blockIdx.x;
  const float* src; u16* dst; int R, C, tc, tr;
  if (b < 64) { src = W1; dst = W1T; R = 256; C = 1024; tc = (b & 15) * 64; tr = (b >> 4) * 64; }
  else { b -= 64; src = W2; dst = W2T; R = 1024; C = 256; tc = (b & 3) * 64; tr = (b >> 2) * 64; }
  const int t = threadIdx.x;
  const int c = t & 63, rb = t >> 6;
#pragma unroll
  for (int i = 0; i < 16; ++i) {
    int r = i * 4 + rb;
    tile[r * 66 + c] = f2bf(src[(size_t)(tr + r) * C + tc + c]);
  }
  __syncthreads();
#pragma unroll
  for (int i = 0; i < 16; ++i) {
    int x = i * 4 + rb;
    int y = c;
    dst[(size_t)(tc + x) * R + tr + y] = tile[y * 66 + x];
  }
}

// ---------------------------------------------------------------------------
// MEGA KERNEL: attention + LN1 + fused FFN + LN2.  One block per board.
// NEW (R9): aw gather with k-ON-LANES -> each instruction's 64 lanes hit one
// 13 KB q-row window (DRAM row locality) instead of 64 scattered q-rows.
// Staged through a 64 KB f32 LDS scratch [q][k^q] (aliases VT+P regions);
// V gathered into registers during softmax, written to VT after scratch
// reads are barrier-protected.
// SMEM layout (78 KB, 2 blocks/CU):
//   [0,64K)    attn: aw scratch f32[64][64][4]  ->  VT (0..32K) | P/Xl (32..64K)
//   [64K,78K)  misc: abt|pno|pidx|redA|redB|red | ffn Hb
// ---------------------------------------------------------------------------
#define SM_BASE 65536
#define OFF_ABT  (SM_BASE + 0)      // f32[676]   2704 B
#define OFF_PNO  (SM_BASE + 2704)   // int[64]     256 B
#define OFF_PIDX (SM_BASE + 2960)   // int[64]     256 B
#define OFF_REDA (SM_BASE + 3216)   // f32[4][4][64] 4096 B
#define OFF_REDB (SM_BASE + 7312)   // f32[4][4][64] 4096 B
#define OFF_RED  (SM_BASE + 11408)  // f32[4][64][2] 2048 B
#define OFF_HB   (SM_BASE + 0)      // u16[64][64] 8192 B (ffn phase only)

__global__ __launch_bounds__(256, 2)
void mega_kernel(const int* __restrict__ piece_indices,
                 const int* __restrict__ abi_idx,
                 const int* __restrict__ ksq,
                 const float* __restrict__ value_table,
                 const float* __restrict__ aw_table,
                 const float* __restrict__ ab_table,
                 const float* __restrict__ scale_p,
                 const float* __restrict__ ln1w, const float* __restrict__ ln1b,
                 const u16* __restrict__ W1T, const u16* __restrict__ W2T,
                 const float* __restrict__ b1, const float* __restrict__ b2,
                 const float* __restrict__ ln2w, const float* __restrict__ ln2b,
                 float* __restrict__ out) {
  __shared__ __align__(16) char SMEM[79872];
  u16* VT = (u16*)(SMEM);            // attn phase (after scratch freed)
  u16* P  = (u16*)(SMEM + 32768);    // attn phase (after scratch freed)
  float* abt_s = (float*)(SMEM + OFF_ABT);
  int* pno_s   = (int*)(SMEM + OFF_PNO);
  int* pidx_s  = (int*)(SMEM + OFF_PIDX);
  float* redA  = (float*)(SMEM + OFF_REDA);  // [kg][h][q]
  float* redB  = (float*)(SMEM + OFF_REDB);
  float* red   = (float*)(SMEM + OFF_RED);   // [w][q2][2]

  const int n = blockIdx.x;
  const int t = threadIdx.x;
  const int h = t >> 6;    // wave id
  const int lane = t & 63;
  const int ks = ksq[n];

  if (t < 64) {
    int pi = piece_indices[n * 64 + t];
    pidx_s[t] = pi;
    pno_s[t] = pi - ks * 832;
  }
  for (int i = t; i < 676; i += 256) abt_s[i] = ab_table[i];
  __syncthreads();

  const float scale = scale_p[0];
  const int q = lane, kg = h;

  // ---- Phase G: aw gather, k on lanes (wave-uniform q-row per instruction) ----
  {
    const int mypno = pno_s[lane];          // k = lane
    const int base = ks * (832 * 832);
    f32x4 awv[16];
#pragma unroll
    for (int j = 0; j < 16; ++j) {
      int qj = h * 16 + j;
      int idx = base + pno_s[qj] * 832 + mypno;
      awv[j] = *(const f32x4*)(aw_table + (size_t)idx * 4);
    }
    // scratch[q][k^q] f32x4: write side fully coalesced (one 1KB row/instr)
#pragma unroll
    for (int j = 0; j < 16; ++j) {
      int qj = h * 16 + j;
      int slot = lane ^ qj;
      *(f32x4*)(SMEM + qj * 1024 + (slot << 4)) = awv[j];
    }
  }
  __syncthreads();  // scratch ready

  // ---- V gather into registers (latency overlaps softmax below) ----
  bf16x8 vreg[8];
  {
    const int feat = t;
#pragma unroll
    for (int c = 0; c < 8; ++c) {
      float tmp[8];
#pragma unroll
      for (int jj = 0; jj < 8; ++jj)
        tmp[jj] = value_table[(size_t)pidx_s[c * 8 + jj] * 256 + feat];
#pragma unroll
      for (int jj = 0; jj < 8; ++jj) vreg[c][jj] = (short)f2bf(tmp[jj]);
    }
  }

  // ---- softmax phase (q on lanes): scratch read + abi bias (coalesced) ----
  float l[4][16];
#pragma unroll
  for (int j = 0; j < 16; ++j) {
    int k = kg * 16 + j;
    f32x4 aw4 = *(const f32x4*)(SMEM + q * 1024 + ((k ^ q) << 4));
    int bi = abi_idx[n * 4096 + k * 64 + q];
    f32x4 ab4 = *(const f32x4*)(abt_s + bi * 4);
#pragma unroll
    for (int hh = 0; hh < 4; ++hh) l[hh][j] = (aw4[hh] + ab4[hh]) * scale;
  }

  // ---- distributed softmax across kg ----
#pragma unroll
  for (int hh = 0; hh < 4; ++hh) {
    float m = l[hh][0];
#pragma unroll
    for (int j = 1; j < 16; ++j) m = fmaxf(m, l[hh][j]);
    redA[(kg * 4 + hh) * 64 + q] = m;
  }
  __syncthreads();  // also: ALL scratch reads complete past this point
  float inv[4];
#pragma unroll
  for (int hh = 0; hh < 4; ++hh) {
    float m = fmaxf(fmaxf(redA[(0 * 4 + hh) * 64 + q], redA[(1 * 4 + hh) * 64 + q]),
                    fmaxf(redA[(2 * 4 + hh) * 64 + q], redA[(3 * 4 + hh) * 64 + q]));
    float s = 0.f;
#pragma unroll
    for (int j = 0; j < 16; ++j) { l[hh][j] = __expf(l[hh][j] - m); s += l[hh][j]; }
    redB[(kg * 4 + hh) * 64 + q] = s;
  }
  __syncthreads();
#pragma unroll
  for (int hh = 0; hh < 4; ++hh)
    inv[hh] = 1.f / (redB[(0 * 4 + hh) * 64 + q] + redB[(1 * 4 + hh) * 64 + q] +
                     redB[(2 * 4 + hh) * 64 + q] + redB[(3 * 4 + hh) * 64 + q]);

  // ---- P write (over scratch rows 32..63) + VT write (rows 0..31) ----
  // safe: two barriers since the last scratch read
#pragma unroll
  for (int hh = 0; hh < 4; ++hh) {
#pragma unroll
    for (int c2 = 0; c2 < 2; ++c2) {
      int c = kg * 2 + c2;
      bf16x8 pv;
#pragma unroll
      for (int j8 = 0; j8 < 8; ++j8) {
        int j = c2 * 8 + j8;
        int k = kg * 16 + j;
        float v = l[hh][j] * inv[hh] + ((k == q) ? 1.f : 0.f);  // +I residual
        pv[j8] = (short)f2bf(v);
      }
      int off = (hh * 64 + q) * 64 + ((c ^ (q & 7)) << 3);
      *(bf16x8*)(&P[off]) = pv;
    }
  }
  {
    const int feat = t;
#pragma unroll
    for (int c = 0; c < 8; ++c) {
      int off = feat * 64 + ((c ^ (feat & 7)) << 3);
      *(bf16x8*)(&VT[off]) = vreg[c];
    }
  }
  __syncthreads();

  // ---- ctx = (P+I) @ V via MFMA; wave h computes head h ----
  const int li = lane & 15, lg = lane >> 4;
  f32x4 acc[4][4] = {};
#pragma unroll
  for (int kst = 0; kst < 2; ++kst) {
    int cg = kst * 4 + lg;
    bf16x8 aF[4], bF[4];
#pragma unroll
    for (int mi = 0; mi < 4; ++mi) {
      int row = mi * 16 + li;
      aF[mi] = *(const bf16x8*)(&P[(h * 64 + row) * 64 + ((cg ^ (row & 7)) << 3)]);
    }
#pragma unroll
    for (int ni = 0; ni < 4; ++ni) {
      int rr = h * 64 + ni * 16 + li;
      bF[ni] = *(const bf16x8*)(&VT[rr * 64 + ((cg ^ (rr & 7)) << 3)]);
    }
#pragma unroll
    for (int mi = 0; mi < 4; ++mi)
#pragma unroll
      for (int ni = 0; ni < 4; ++ni)
        acc[mi][ni] = __builtin_amdgcn_mfma_f32_16x16x32_bf16(aF[mi], bF[ni], acc[mi][ni], 0, 0, 0);
  }

  // ---- LN1 ----
#pragma unroll
  for (int mi = 0; mi < 4; ++mi)
#pragma unroll
    for (int r = 0; r < 4; ++r) {
      float s1 = 0.f, s2 = 0.f;
#pragma unroll
      for (int ni = 0; ni < 4; ++ni) { float v = acc[mi][ni][r]; s1 += v; s2 += v * v; }
#pragma unroll
      for (int mk = 1; mk < 16; mk <<= 1) { s1 += __shfl_xor(s1, mk, 64); s2 += __shfl_xor(s2, mk, 64); }
      if (li == 0) { int q2 = mi * 16 + lg * 4 + r; red[(h * 64 + q2) * 2 + 0] = s1; red[(h * 64 + q2) * 2 + 1] = s2; }
    }
  __syncthreads();   // all MFMA reads of P/VT done; red ready

  // x (LN1 out) -> Xl (aliases P region), FFN swizzled layout
  u16* Xl = (u16*)(SMEM + 32768);
  {
    float w_[4], b_[4];
#pragma unroll
    for (int ni = 0; ni < 4; ++ni) {
      int f = h * 64 + ni * 16 + li;
      w_[ni] = ln1w[f]; b_[ni] = ln1b[f];
    }
#pragma unroll
    for (int mi = 0; mi < 4; ++mi)
#pragma unroll
      for (int r = 0; r < 4; ++r) {
        int q2 = mi * 16 + lg * 4 + r;
        float S1 = red[(0 * 64 + q2) * 2] + red[(1 * 64 + q2) * 2] +
                   red[(2 * 64 + q2) * 2] + red[(3 * 64 + q2) * 2];
        float S2 = red[(0 * 64 + q2) * 2 + 1] + red[(1 * 64 + q2) * 2 + 1] +
                   red[(2 * 64 + q2) * 2 + 1] + red[(3 * 64 + q2) * 2 + 1];
        float mean = S1 * (1.f / 256.f);
        float var = S2 * (1.f / 256.f) - mean * mean;
        float rs = rsqrtf(var + 1e-5f);
#pragma unroll
        for (int ni = 0; ni < 4; ++ni) {
          int col = h * 64 + ni * 16 + li;
          float xv = (acc[mi][ni][r] - mean) * rs * w_[ni] + b_[ni];
          int cc = col >> 3;
          *(u16*)((char*)Xl + q2 * 512 + (((cc ^ (q2 & 7)) & 31) << 4) + (col & 7) * 2) = f2bf(xv);
        }
      }
  }

  // =================== FFN phase ===================
  u16* Wb = (u16*)(SMEM);           // aliases dead VT
  u16* Hb = (u16*)(SMEM + OFF_HB);  // aliases dead abt/redA
  const int wv = h;
  f32x4 oacc[4][4] = {};

  for (int ch = 0; ch < 16; ++ch) {
    // stage W1T chunk [64][256]
#pragma unroll
    for (int it = 0; it < 8; ++it) {
      int idx = it * 256 + t;
      int row = idx >> 5, c = idx & 31;
      const u16* g = W1T + (size_t)(ch * 64 + row) * 256 + (((c ^ (row & 7)) & 31) << 3);
      gload_lds16(g, (char*)Wb + it * 4096 + wv * 1024);
    }
    __syncthreads();  // Xl writes (+first iter) / prev GEMM2 reads + stage drain

    // GEMM1: wave wv computes H cols [wv*16, wv*16+16), K=256
    f32x4 hacc[4] = {};
#pragma unroll
    for (int kst = 0; kst < 8; ++kst) {
      int cg = kst * 4 + lg;
      bf16x8 aF[4], bF;
      {
        int brow = wv * 16 + li;
        bF = *(const bf16x8*)((char*)Wb + brow * 512 + (((cg ^ (brow & 7)) & 31) << 4));
      }
#pragma unroll
      for (int mi = 0; mi < 4; ++mi) {
        int row = mi * 16 + li;
        aF[mi] = *(const bf16x8*)((char*)Xl + row * 512 + (((cg ^ (row & 7)) & 31) << 4));
      }
#pragma unroll
      for (int mi = 0; mi < 4; ++mi)
        hacc[mi] = __builtin_amdgcn_mfma_f32_16x16x32_bf16(aF[mi], bF, hacc[mi], 0, 0, 0);
    }
    __syncthreads();  // W1Tc reads done; Hb free

    // relu + bias -> H chunk LDS; stage W2T chunk into Wb
    {
      float bv = b1[ch * 64 + wv * 16 + li];
      int col = wv * 16 + li;
      int c2 = col >> 3;
#pragma unroll
      for (int mi = 0; mi < 4; ++mi)
#pragma unroll
        for (int r = 0; r < 4; ++r) {
          int row = mi * 16 + lg * 4 + r;
          float v = fmaxf(hacc[mi][r] + bv, 0.f);
          *(u16*)((char*)Hb + row * 128 + ((c2 ^ (row & 7)) << 4) + (col & 7) * 2) = f2bf(v);
        }
    }
#pragma unroll
    for (int it = 0; it < 8; ++it) {
      int idx = it * 256 + t;
      int row = idx >> 3, c = idx & 7;
      const u16* g = W2T + (size_t)row * 1024 + ch * 64 + ((c ^ (row & 7)) << 3);
      gload_lds16(g, (char*)Wb + it * 4096 + wv * 1024);
    }
    __syncthreads();  // H + W2Tc ready

    // GEMM2 partial: oacc += H(64x64) @ W2Tc
#pragma unroll
    for (int kst = 0; kst < 2; ++kst) {
      int cg = kst * 4 + lg;
      bf16x8 aF[4], bF[4];
#pragma unroll
      for (int mi = 0; mi < 4; ++mi) {
        int row = mi * 16 + li;
        aF[mi] = *(const bf16x8*)((char*)Hb + row * 128 + (((cg ^ (row & 7)) & 7) << 4));
      }
#pragma unroll
      for (int ni = 0; ni < 4; ++ni) {
        int row = wv * 64 + ni * 16 + li;
        bF[ni] = *(const bf16x8*)((char*)Wb + row * 128 + (((cg ^ (row & 7)) & 7) << 4));
      }
#pragma unroll
      for (int mi = 0; mi < 4; ++mi)
#pragma unroll
        for (int ni = 0; ni < 4; ++ni)
          oacc[mi][ni] = __builtin_amdgcn_mfma_f32_16x16x32_bf16(aF[mi], bF[ni], oacc[mi][ni], 0, 0, 0);
    }
    __syncthreads();  // Wb/Hb reads done -> next chunk overwrite safe
  }

  // ---- epilogue: bias + residual (from Xl) + LN2 ----
  float bias2[4];
#pragma unroll
  for (int ni = 0; ni < 4; ++ni) bias2[ni] = b2[wv * 64 + ni * 16 + li];

#pragma unroll
  for (int mi = 0; mi < 4; ++mi)
#pragma unroll
    for (int r = 0; r < 4; ++r) {
      float s1 = 0.f, s2 = 0.f;
      int row = mi * 16 + lg * 4 + r;
#pragma unroll
      for (int ni = 0; ni < 4; ++ni) {
        int col = wv * 64 + ni * 16 + li;
        int cc = col >> 3;
        u16 xres = *(const u16*)((char*)Xl + row * 512 + (((cc ^ (row & 7)) & 31) << 4) + (col & 7) * 2);
        float v = oacc[mi][ni][r] + bias2[ni] + bf2f(xres);
        oacc[mi][ni][r] = v;
        s1 += v; s2 += v * v;
      }
#pragma unroll
      for (int mk = 1; mk < 16; mk <<= 1) { s1 += __shfl_xor(s1, mk, 64); s2 += __shfl_xor(s2, mk, 64); }
      if (li == 0) { int q2 = mi * 16 + lg * 4 + r; red[(wv * 64 + q2) * 2 + 0] = s1; red[(wv * 64 + q2) * 2 + 1] = s2; }
    }
  __syncthreads();

  float lw[4], lb[4];
#pragma unroll
  for (int ni = 0; ni < 4; ++ni) {
    int col = wv * 64 + ni * 16 + li;
    lw[ni] = ln2w[col]; lb[ni] = ln2b[col];
  }
#pragma unroll
  for (int mi = 0; mi < 4; ++mi)
#pragma unroll
    for (int r = 0; r < 4; ++r) {
      int q2 = mi * 16 + lg * 4 + r;
      float S1 = red[(0 * 64 + q2) * 2] + red[(1 * 64 + q2) * 2] +
                 red[(2 * 64 + q2) * 2] + red[(3 * 64 + q2) * 2];
      float S2 = red[(0 * 64 + q2) * 2 + 1] + red[(1 * 64 + q2) * 2 + 1] +
                 red[(2 * 64 + q2) * 2 + 1] + red[(3 * 64 + q2) * 2 + 1];
      float mean = S1 * (1.f / 256.f);
      float var = S2 * (1.f / 256.f) - mean * mean;
      float rs = rsqrtf(var + 1e-5f);
      size_t rbase = (size_t)(n * 64 + q2) * 256;
#pragma unroll
      for (int ni = 0; ni < 4; ++ni)
        out[rbase + wv * 64 + ni * 16 + li] = (oacc[mi][ni][r] - mean) * rs * lw[ni] + lb[ni];
    }
}

// ---------------------------------------------------------------------------
extern "C" void kernel_launch(void* const* d_in, const int* in_sizes, int n_in,
                              void* d_out, int out_size, void* d_ws, size_t ws_size,
                              hipStream_t stream) {
  const int* piece_indices = (const int*)d_in[0];
  const int* abi_idx       = (const int*)d_in[1];
  const int* ksq           = (const int*)d_in[2];
  const float* value_table = (const float*)d_in[3];
  const float* aw_table    = (const float*)d_in[4];
  const float* ab_table    = (const float*)d_in[5];
  const float* attn_scale  = (const float*)d_in[6];
  const float* W1          = (const float*)d_in[7];
  const float* b1          = (const float*)d_in[8];
  const float* W2          = (const float*)d_in[9];
  const float* b2          = (const float*)d_in[10];
  const float* ln1w        = (const float*)d_in[11];
  const float* ln1b        = (const float*)d_in[12];
  const float* ln2w        = (const float*)d_in[13];
  const float* ln2b        = (const float*)d_in[14];

  char* ws = (char*)d_ws;
  u16* W1T = (u16*)(ws);                 // 512 KB  [1024][256] bf16
  u16* W2T = (u16*)(ws + (512 << 10));   // 512 KB  [256][1024] bf16
  float* out = (float*)d_out;

  transpose_kernel<<<128, 256, 0, stream>>>(W1, W1T, W2, W2T);
  mega_kernel<<<512, 256, 0, stream>>>(piece_indices, abi_idx, ksq, value_table,
                                       aw_table, ab_table, attn_scale, ln1w, ln1b,
                                       W1T, W2T, b1, b2, ln2w, ln2b, out);
}